// Round 4
// baseline (2690.407 us; speedup 1.0000x reference)
//
#include <hip/hip_runtime.h>

// QLSTM: T=512, B=64, D=512, H=512.
// Phase A: gx[tb][2560] = bf16( X@[Wx|Wr]^T + bias )  (gates x-part + residual)
// Phase B: persistent 32-block kernel, 512 steps.
//   R2: agent-scope atomics instead of __threadfence (was 11.6us/step).
//   R3: single-round-trip staging (was 8 serialized round trips).
//   R4: SELF-VALIDATING DATA. h published as dword = (bf16(h)<<16) | step_tag.
//       Consumers poll the data itself with sc0/sc1 loads until all low16 == t.
//       Eliminates producer drain + flag store + flag-poll round-trip from the
//       critical path. Double-buffered slots; tags make overwrite races
//       impossible: a producer writes tag t+2 into a slot only after observing
//       ALL blocks' tag t+1 publications, which happen only after those blocks
//       fully consumed tag t from that slot.
//   Block = 512 threads (8 waves): wave w -> gate pair (w&1), batch quarter
//   (w>>1, 16 rows). Poll buffer = 16 granules/thread = 64 VGPR.

typedef __bf16         bfrag8 __attribute__((ext_vector_type(8)));
typedef float          f32x4v __attribute__((ext_vector_type(4)));
typedef unsigned short u16x8  __attribute__((ext_vector_type(8)));
typedef int            v4i    __attribute__((ext_vector_type(4)));
typedef int            v2i    __attribute__((ext_vector_type(2)));

#define N_TB    32768   // T*B
#define GXW     2560    // 4*512 gate rows + 512 residual rows
#define OUT_HX  16777216
#define OUT_CX  16809984

__device__ __forceinline__ float bf2f(unsigned short u) {
  unsigned int x = ((unsigned int)u) << 16;
  return __builtin_bit_cast(float, x);
}
__device__ __forceinline__ unsigned short f2bf(float f) {
  unsigned int x = __builtin_bit_cast(unsigned int, f);
  x = x + 0x7FFFu + ((x >> 16) & 1u);   // RNE
  return (unsigned short)(x >> 16);
}
__device__ __forceinline__ float sigf(float x) {
  x = fminf(fmaxf(x, -30.f), 30.f);
  return 1.f / (1.f + __expf(-x));
}
__device__ __forceinline__ float tanh_f(float x) {
  x = fminf(fmaxf(x, -15.f), 15.f);
  float e = __expf(-2.f * x);
  return (1.f - e) / (1.f + e);
}

// ---------- K1: f32 -> bf16 convert (inputs -> X) ----------
__global__ void cvt_kernel(const float* __restrict__ in, unsigned short* __restrict__ out) {
  int i = (blockIdx.x * 256 + threadIdx.x) * 4;
  float4 v = *(const float4*)(in + i);
  ushort4 o = make_ushort4(f2bf(v.x), f2bf(v.y), f2bf(v.z), f2bf(v.w));
  *(ushort4*)(out + i) = o;
}

// ---------- K2: weight repack f32->bf16 ----------
__global__ void repack_kernel(const float* __restrict__ Wf, const float* __restrict__ Wi,
                              const float* __restrict__ Wg, const float* __restrict__ Wo,
                              const float* __restrict__ Wr,
                              const float* __restrict__ bfp, const float* __restrict__ bip,
                              const float* __restrict__ bgp, const float* __restrict__ bop,
                              const float* __restrict__ brp,
                              unsigned short* __restrict__ Wc, unsigned short* __restrict__ Whx,
                              float* __restrict__ bias) {
  int tid = blockIdx.x * 256 + threadIdx.x;
  if (tid < 262144) {                    // gate rows: 2048 rows x 128 quads
    int row = tid >> 7;
    int k4  = (tid & 127) * 4;
    int g = row >> 9, h = row & 511;
    const float* W = (g == 0) ? Wf : (g == 1) ? Wi : (g == 2) ? Wg : Wo;
    float4 a = *(const float4*)(W + (size_t)h * 1024 + k4);
    float4 b = *(const float4*)(W + (size_t)h * 1024 + 512 + k4);
    *(ushort4*)(Wc  + (size_t)row * 512 + k4) = make_ushort4(f2bf(a.x), f2bf(a.y), f2bf(a.z), f2bf(a.w));
    *(ushort4*)(Whx + (size_t)row * 512 + k4) = make_ushort4(f2bf(b.x), f2bf(b.y), f2bf(b.z), f2bf(b.w));
  } else if (tid < 327680) {             // residual rows
    int t2 = tid - 262144;
    int row = t2 >> 7;
    int k4  = (t2 & 127) * 4;
    float4 a = *(const float4*)(Wr + (size_t)row * 512 + k4);
    *(ushort4*)(Wc + (size_t)(2048 + row) * 512 + k4) =
        make_ushort4(f2bf(a.x), f2bf(a.y), f2bf(a.z), f2bf(a.w));
  }
  if (tid < 2560) {
    float v;
    if      (tid <  512) v = bfp[tid];
    else if (tid < 1024) v = bip[tid - 512];
    else if (tid < 1536) v = bgp[tid - 1024];
    else if (tid < 2048) v = bop[tid - 1536];
    else                 v = brp[tid - 2048];
    bias[tid] = v;
  }
}

// ---------- K3: GEMM  C[n][m] = bf16( sum_k A[m][k]*B[n][k] + bias[m] ) ----------
__global__ __launch_bounds__(256)
void gemm_kernel(const unsigned short* __restrict__ A, const unsigned short* __restrict__ B,
                 const float* __restrict__ bias, unsigned short* __restrict__ C) {
  const int bm = blockIdx.x;       // 0..19
  const int bn = blockIdx.y;       // 0..255
  const int tid = threadIdx.x;
  const int lane = tid & 63;
  const int w = tid >> 6;
  const int wm = w & 1, wn = w >> 1;
  const int col = lane & 15, q = lane >> 4;

  __shared__ unsigned short As[128 * 64] __attribute__((aligned(16)));
  __shared__ unsigned short Bs[128 * 64] __attribute__((aligned(16)));

  f32x4v acc[4][4] = {};

  for (int kt = 0; kt < 8; ++kt) {
    __syncthreads();
    #pragma unroll
    for (int p = 0; p < 4; ++p) {
      int idx = p * 256 + tid;          // 16B granule id
      int row = idx >> 3, gc = idx & 7;
      *(u16x8*)(&As[idx * 8]) = *(const u16x8*)(A + (size_t)(bm * 128 + row) * 512 + kt * 64 + gc * 8);
      *(u16x8*)(&Bs[idx * 8]) = *(const u16x8*)(B + (size_t)(bn * 128 + row) * 512 + kt * 64 + gc * 8);
    }
    __syncthreads();
    #pragma unroll
    for (int kk = 0; kk < 2; ++kk) {
      bfrag8 af[4], bfr[4];
      #pragma unroll
      for (int mt = 0; mt < 4; ++mt)
        af[mt] = *(const bfrag8*)(&As[(wm * 64 + mt * 16 + col) * 64 + kk * 32 + q * 8]);
      #pragma unroll
      for (int nt = 0; nt < 4; ++nt)
        bfr[nt] = *(const bfrag8*)(&Bs[(wn * 64 + nt * 16 + col) * 64 + kk * 32 + q * 8]);
      #pragma unroll
      for (int mt = 0; mt < 4; ++mt)
        #pragma unroll
        for (int nt = 0; nt < 4; ++nt)
          acc[mt][nt] = __builtin_amdgcn_mfma_f32_16x16x32_bf16(af[mt], bfr[nt], acc[mt][nt], 0, 0, 0);
    }
  }
  #pragma unroll
  for (int mt = 0; mt < 4; ++mt) {
    const int m0 = bm * 128 + wm * 64 + mt * 16 + q * 4;
    const float4 b4 = *(const float4*)(bias + m0);
    #pragma unroll
    for (int nt = 0; nt < 4; ++nt) {
      const int n = bn * 128 + wn * 64 + nt * 16 + col;
      f32x4v v = acc[mt][nt];
      ushort4 o = make_ushort4(f2bf(v[0] + b4.x), f2bf(v[1] + b4.y),
                               f2bf(v[2] + b4.z), f2bf(v[3] + b4.w));
      *(ushort4*)(C + (size_t)n * GXW + m0) = o;
    }
  }
}

// ---------- K4: persistent recurrent kernel ----------
// 32 blocks x 512 threads. Block jb owns h_out cols [jb*16, jb*16+16).
// hbufF: 2 slots x 32768 dwords; dword = (bf16(h)<<16) | tag.
// Iter t: consume slot t&1 with tag==t (slot0 init zeros = tag 0, h=0);
//         publish h_t to slot (t+1)&1 with tag t+1 (t<511).
__global__ __launch_bounds__(512, 1)
void recur_kernel(const unsigned short* __restrict__ Whx, const unsigned short* __restrict__ gx,
                  unsigned int* __restrict__ hbufF, float* __restrict__ out) {
  const int jb = blockIdx.x;
  const int tid = threadIdx.x;          // 0..511
  const int lane = tid & 63;
  const int w = tid >> 6;               // 0..7
  const int gp = w & 1;                 // gate pair
  const int mh = w >> 1;                // batch quarter (16 rows)
  const int col = lane & 15;
  const int q = lane >> 4;

  __shared__ float S[4][64][20] __attribute__((aligned(16)));           // stride 20: 2-way banks
  __shared__ unsigned short Hs[64][520] __attribute__((aligned(16)));   // [batch][k], +8 pad

  // Static recurrent-weight B-fragments: 2 gates x 16 k-tiles (64 VGPR, live all 512 steps).
  bfrag8 Bf[2][16];
  #pragma unroll
  for (int g2 = 0; g2 < 2; ++g2) {
    const int gate = gp * 2 + g2;
    const unsigned short* wp = Whx + (size_t)(gate * 512 + jb * 16 + col) * 512 + q * 8;
    #pragma unroll
    for (int kk = 0; kk < 16; ++kk)
      Bf[g2][kk] = *(const bfrag8*)(wp + kk * 32);
  }

  // Update-phase mapping: thread -> (batch ub, 2 cols starting at uc)
  const int ub = tid >> 3;              // 0..63
  const int uc = (tid & 7) * 2;         // 0,2,..,14

  float c2[2] = {0.f, 0.f};

  // prefetch gx/res for t=0
  ushort2 gxv[4], rv;
  {
    const unsigned short* g0 = gx + (size_t)ub * GXW + jb * 16 + uc;
    #pragma unroll
    for (int gg = 0; gg < 4; ++gg) gxv[gg] = *(const ushort2*)(g0 + gg * 512);
    rv = *(const ushort2*)(g0 + 2048);
  }

  for (int t = 0; t < 512; ++t) {
    // ---- Poll + stage h_{t-1}: data IS the flag (low16 of each dword == t).
    {
      const char* hs = (const char*)(hbufF + (t & 1) * 32768);
      v4i ta[8], tb_[8];
      const int need = (t > 0);
      for (;;) {
        #pragma unroll
        for (int i = 0; i < 8; ++i) {
          const char* p = hs + (size_t)(i * 512 + tid) * 32;   // 8-dword unit
          asm volatile("global_load_dwordx4 %0, %1, off sc0 sc1"
                       : "=v"(ta[i]) : "v"(p) : "memory");
          asm volatile("global_load_dwordx4 %0, %1, off sc0 sc1"
                       : "=v"(tb_[i]) : "v"(p + 16) : "memory");
        }
        asm volatile("s_waitcnt vmcnt(0)" ::: "memory");
        if (!need) break;
        unsigned int bad = 0;
        #pragma unroll
        for (int i = 0; i < 8; ++i)
          #pragma unroll
          for (int j = 0; j < 4; ++j) {
            bad |= (unsigned int)(ta[i][j]  ^ t) & 0xFFFFu;
            bad |= (unsigned int)(tb_[i][j] ^ t) & 0xFFFFu;
          }
        if (!bad) break;
      }
      // repack 8 f32-tagged dword-pairs -> bf16 granules, write LDS
      #pragma unroll
      for (int i = 0; i < 8; ++i) {
        const int u = i * 512 + tid;       // unit id; bf16 granule id == u
        v4i o;
        o[0] = (int)(((unsigned int)ta[i][0]  >> 16) | ((unsigned int)ta[i][1]  & 0xFFFF0000u));
        o[1] = (int)(((unsigned int)ta[i][2]  >> 16) | ((unsigned int)ta[i][3]  & 0xFFFF0000u));
        o[2] = (int)(((unsigned int)tb_[i][0] >> 16) | ((unsigned int)tb_[i][1] & 0xFFFF0000u));
        o[3] = (int)(((unsigned int)tb_[i][2] >> 16) | ((unsigned int)tb_[i][3] & 0xFFFF0000u));
        *(v4i*)((char*)&Hs[0][0] + (size_t)(u >> 6) * 1040 + (u & 63) * 16) = o;
      }
    }
    __syncthreads();

    // ---- S = h_{t-1} @ Whx_slice^T  (A-frags from LDS, B-frags static)
    bfrag8 Af[16];
    {
      const unsigned short* ap = &Hs[mh * 16 + col][q * 8];
      #pragma unroll
      for (int kk = 0; kk < 16; ++kk)
        Af[kk] = *(const bfrag8*)(ap + kk * 32);
    }
    f32x4v acc[2] = {};
    #pragma unroll
    for (int kk = 0; kk < 16; ++kk) {
      acc[0] = __builtin_amdgcn_mfma_f32_16x16x32_bf16(Af[kk], Bf[0][kk], acc[0], 0, 0, 0);
      acc[1] = __builtin_amdgcn_mfma_f32_16x16x32_bf16(Af[kk], Bf[1][kk], acc[1], 0, 0, 0);
    }
    #pragma unroll
    for (int g2 = 0; g2 < 2; ++g2) {
      const int gate = gp * 2 + g2;
      const int b0 = mh * 16 + q * 4;
      #pragma unroll
      for (int r = 0; r < 4; ++r)
        S[gate][b0 + r][col] = acc[g2][r];
    }
    __syncthreads();

    // ---- elementwise gate/update (512 threads x 2 cells)
    float pre[4][2];
    #pragma unroll
    for (int gg = 0; gg < 4; ++gg) {
      float2 sv = *(const float2*)&S[gg][ub][uc];
      pre[gg][0] = sv.x + bf2f(gxv[gg].x);
      pre[gg][1] = sv.y + bf2f(gxv[gg].y);
    }
    float rres[2] = {bf2f(rv.x), bf2f(rv.y)};
    float hv[2];
    #pragma unroll
    for (int j = 0; j < 2; ++j) {
      float fg = sigf(pre[0][j]);
      float ig = sigf(pre[1][j]);
      float gg = tanh_f(pre[2][j]);
      float og = sigf(pre[3][j]);
      c2[j] = fg * c2[j] + ig * gg;
      hv[j] = og * tanh_f(c2[j]) + rres[j];
    }

    if (t < 511) {
      // Publish h_t immediately: tagged dwords, no drain, no flag.
      v2i pk;
      pk[0] = (int)(((unsigned int)f2bf(hv[0]) << 16) | (unsigned int)(t + 1));
      pk[1] = (int)(((unsigned int)f2bf(hv[1]) << 16) | (unsigned int)(t + 1));
      unsigned int* dst = hbufF + ((t + 1) & 1) * 32768 + ub * 512 + jb * 16 + uc;
      asm volatile("global_store_dwordx2 %0, %1, off sc0 sc1"
                   :: "v"(dst), "v"(pk) : "memory");
    }

    // Off-critical-path stores.
    *(float2*)(out + (size_t)t * 32768 + ub * 512 + jb * 16 + uc) = make_float2(hv[0], hv[1]);

    if (t == 511) {
      *(float2*)(out + OUT_HX + ub * 512 + jb * 16 + uc) = make_float2(hv[0], hv[1]);
      *(float2*)(out + OUT_CX + ub * 512 + jb * 16 + uc) = make_float2(c2[0], c2[1]);
    } else {
      // prefetch gx/res for t+1 (completes under next poll's vmcnt)
      const unsigned short* gn = gx + (size_t)((t + 1) * 64 + ub) * GXW + jb * 16 + uc;
      #pragma unroll
      for (int gg = 0; gg < 4; ++gg) gxv[gg] = *(const ushort2*)(gn + gg * 512);
      rv = *(const ushort2*)(gn + 2048);
    }
  }
}

extern "C" void kernel_launch(void* const* d_in, const int* in_sizes, int n_in,
                              void* d_out, int out_size, void* d_ws, size_t ws_size,
                              hipStream_t stream) {
  const float* inputs = (const float*)d_in[0];
  const float* Wf = (const float*)d_in[1];
  const float* bf_ = (const float*)d_in[2];
  const float* Wi = (const float*)d_in[3];
  const float* bi_ = (const float*)d_in[4];
  const float* Wg = (const float*)d_in[5];
  const float* bg_ = (const float*)d_in[6];
  const float* Wo = (const float*)d_in[7];
  const float* bo_ = (const float*)d_in[8];
  const float* Wr = (const float*)d_in[9];
  const float* br_ = (const float*)d_in[10];
  float* out = (float*)d_out;

  // workspace layout (all 16B-aligned)
  unsigned short* X    = (unsigned short*)d_ws;        // 16777216 el (dead after gemm)
  unsigned short* Wc   = X + 16777216;                 // 1310720 el
  unsigned short* Whx  = Wc + 1310720;                 // 1048576 el
  float*          bias = (float*)(Whx + 1048576);      // 2560 el
  unsigned short* gx   = (unsigned short*)(bias + 2560);  // 83886080 el
  unsigned int*   hbufF = (unsigned int*)d_ws;         // 2 x 32768 dwords, ALIASES X
  const size_t ws_needed = 206055424;
  if (ws_size < ws_needed) return;   // fail visibly rather than corrupt

  cvt_kernel<<<16384, 256, 0, stream>>>(inputs, X);
  repack_kernel<<<1280, 256, 0, stream>>>(Wf, Wi, Wg, Wo, Wr, bf_, bi_, bg_, bo_, br_,
                                          Wc, Whx, bias);
  gemm_kernel<<<dim3(20, 256), 256, 0, stream>>>(Wc, X, bias, gx);
  // X is dead now; zero the h exchange buffer that aliases it (slot0 = h0=0/tag0,
  // slot1 = tag0 too, so the t=1 poll for tag==1 can never false-positive).
  hipMemsetAsync(hbufF, 0, 2 * 32768 * 4, stream);
  recur_kernel<<<32, 512, 0, stream>>>(Whx, gx, hbufF, out);
}